// Round 1
// baseline (1470.589 us; speedup 1.0000x reference)
//
#include <hip/hip_runtime.h>
#include <hip/hip_bf16.h>
#include <stdint.h>

typedef __attribute__((ext_vector_type(4))) float f32x4;
typedef __attribute__((ext_vector_type(8))) short bf16x8;
typedef __attribute__((ext_vector_type(8))) unsigned short ushort8;
typedef __attribute__((ext_vector_type(4))) unsigned short ushort4v;

#define BM 128
#define BN 128
#define BK 64
#define NT 256

// round-to-nearest-even f32 -> bf16 (bit trick, 3 VALU ops)
__device__ __forceinline__ unsigned short f2bf(float f) {
    union { float f; unsigned int u; } v; v.f = f;
    unsigned int u = v.u;
    u += 0x7FFFu + ((u >> 16) & 1u);
    return (unsigned short)(u >> 16);
}

// swizzled element index in a [rows][BK] bf16 tile.
// byte = (row*BK + k)*2 ; swizzle: byte ^= (row&7)<<4  => elem ^= (row&7)<<3
// keeps 8-elem (16B) blocks intact; spreads 16 consecutive rows over 8 bank slots (2-way = free)
__device__ __forceinline__ int swz(int row, int k) {
    return (row * BK + k) ^ ((row & 7) << 3);
}

__global__ __launch_bounds__(NT, 2)
void qgemm(const float* __restrict__ X, const int* __restrict__ QW,
           const float* __restrict__ SC, const int* __restrict__ QZ,
           const float* __restrict__ BIAS, float* __restrict__ OUT,
           int M, int N, int K)
{
    __shared__ __align__(16) unsigned short As[2][BM * BK];
    __shared__ __align__(16) unsigned short Bs[2][BN * BK];

    const int ntn = N / BN;
    const int bm = (blockIdx.x / ntn) * BM;
    const int bn = (blockIdx.x % ntn) * BN;

    const int tid  = threadIdx.x;
    const int lane = tid & 63;
    const int wave = tid >> 6;          // 0..3, arranged 2x2
    const int wm = (wave >> 1) * 64;    // wave row offset in tile
    const int wn = (wave & 1) * 64;     // wave col offset in tile
    const int lr = lane & 15;           // fragment row/col within 16
    const int lk = (lane >> 4) * 8;     // fragment k offset

    // staging decomposition
    const int a_c4 = tid & 15;          // which float4 along K (16 float4 per row of 64)
    const int a_r0 = tid >> 4;          // row 0..15, +16 per pass (8 passes)
    const int b_n  = tid & 127;         // B column owned by this thread (fixed)
    const int b_k0 = tid >> 7;          // 0/1 ; ko = b_k0 + 2*pass

    f32x4 acc[4][4] = {};

    float4 va[8];
    unsigned int wb[4];
    float sc_s = 0.f, sc_zb = 0.f;

    const int nk = K / BK;

    auto gload = [&](int t) {
        const int k0 = t * BK;
        #pragma unroll
        for (int p = 0; p < 8; ++p) {
            const float* src = X + (size_t)(bm + a_r0 + p * 16) * K + k0 + a_c4 * 4;
            va[p] = *reinterpret_cast<const float4*>(src);
        }
        const int g  = k0 >> 7;             // GROUP=128, BK=64 -> group constant per tile
        const int gn = bn + b_n;
        sc_s = SC[(size_t)g * N + gn];
        const int zq = ((QZ[(size_t)g * (N >> 3) + (gn >> 3)] >> ((gn & 7) * 4)) & 15) + 1;
        sc_zb = -(float)zq * sc_s;          // W = q*s + zb
        #pragma unroll
        for (int p = 0; p < 4; ++p) {
            const int ko = b_k0 + p * 2;    // k-octet 0..7
            wb[p] = (unsigned int)QW[(size_t)(t * 8 + ko) * N + gn];
        }
    };

    auto lwrite = [&](int buf) {
        #pragma unroll
        for (int p = 0; p < 8; ++p) {
            const int row = a_r0 + p * 16;
            ushort4v b;
            b.x = f2bf(va[p].x); b.y = f2bf(va[p].y);
            b.z = f2bf(va[p].z); b.w = f2bf(va[p].w);
            *reinterpret_cast<ushort4v*>(&As[buf][swz(row, a_c4 * 4)]) = b;
        }
        #pragma unroll
        for (int p = 0; p < 4; ++p) {
            const int ko = b_k0 + p * 2;
            ushort8 o;
            #pragma unroll
            for (int j = 0; j < 8; ++j) {
                const float q = (float)((wb[p] >> (4 * j)) & 15u);
                o[j] = f2bf(fmaf(q, sc_s, sc_zb));
            }
            *reinterpret_cast<ushort8*>(&Bs[buf][swz(b_n, ko * 8)]) = o;
        }
    };

    auto compute = [&](int buf) {
        #pragma unroll
        for (int kk = 0; kk < 2; ++kk) {
            bf16x8 af[4], bfr[4];
            #pragma unroll
            for (int i = 0; i < 4; ++i) {
                af[i]  = *reinterpret_cast<const bf16x8*>(&As[buf][swz(wm + i * 16 + lr, kk * 32 + lk)]);
                bfr[i] = *reinterpret_cast<const bf16x8*>(&Bs[buf][swz(wn + i * 16 + lr, kk * 32 + lk)]);
            }
            #pragma unroll
            for (int i = 0; i < 4; ++i)
                #pragma unroll
                for (int j = 0; j < 4; ++j)
                    acc[i][j] = __builtin_amdgcn_mfma_f32_16x16x32_bf16(af[i], bfr[j], acc[i][j], 0, 0, 0);
        }
    };

    gload(0);
    lwrite(0);
    __syncthreads();

    for (int t = 0; t < nk; ++t) {
        if (t + 1 < nk) gload(t + 1);       // issue next-tile global loads early (T14)
        compute(t & 1);                     // MFMA on current buffer hides load latency
        if (t + 1 < nk) lwrite((t + 1) & 1);// convert/dequant + ds_write to other buffer
        __syncthreads();                    // one barrier per iteration (double buffer)
    }

    // epilogue: C/D layout col=lane&15, row=(lane>>4)*4+reg (verified m89/m91)
    #pragma unroll
    for (int i = 0; i < 4; ++i) {
        #pragma unroll
        for (int j = 0; j < 4; ++j) {
            const int col = bn + wn + j * 16 + lr;
            const float b = BIAS[col];
            #pragma unroll
            for (int r = 0; r < 4; ++r) {
                const int row = bm + wm + i * 16 + (lane >> 4) * 4 + r;
                OUT[(size_t)row * N + col] = acc[i][j][r] + b;
            }
        }
    }
}

extern "C" void kernel_launch(void* const* d_in, const int* in_sizes, int n_in,
                              void* d_out, int out_size, void* d_ws, size_t ws_size,
                              hipStream_t stream) {
    const float* X    = (const float*)d_in[0];
    const int*   QW   = (const int*)d_in[1];
    const float* SC   = (const float*)d_in[2];
    const int*   QZ   = (const int*)d_in[3];
    const float* BIAS = (const float*)d_in[4];
    float* OUT = (float*)d_out;

    const int N = in_sizes[4];                        // 11008
    const long long qwsz = in_sizes[1];               // (K/8)*N
    const int K = (int)(qwsz * 8 / N);                // 4096
    const int M = in_sizes[0] / K;                    // 8192

    dim3 grid((M / BM) * (N / BN));
    qgemm<<<grid, NT, 0, stream>>>(X, QW, SC, QZ, BIAS, OUT, M, N, K);
}

// Round 2
// 1091.341 us; speedup vs baseline: 1.3475x; 1.3475x over previous
//
#include <hip/hip_runtime.h>
#include <hip/hip_bf16.h>
#include <stdint.h>

typedef __attribute__((ext_vector_type(4))) float f32x4;
typedef __attribute__((ext_vector_type(8))) short bf16x8;
typedef __attribute__((ext_vector_type(8))) unsigned short ushort8;
typedef __attribute__((ext_vector_type(4))) unsigned short ushort4v;

// round-to-nearest-even f32 -> bf16
__device__ __forceinline__ unsigned short f2bf(float f) {
    union { float f; unsigned int u; } v; v.f = f;
    unsigned int u = v.u;
    u += 0x7FFFu + ((u >> 16) & 1u);
    return (unsigned short)(u >> 16);
}

// swizzled element index in a [rows][64] bf16 tile: elem ^= (row&7)<<3
// (byte ^= (row&7)<<4; keeps 16B blocks intact, kills the 128B-row-stride conflict)
__device__ __forceinline__ int swz(int row, int k) {
    return (row * 64 + k) ^ ((row & 7) << 3);
}

__device__ __forceinline__ void gld16(const void* g, void* l) {
    __builtin_amdgcn_global_load_lds(
        (const __attribute__((address_space(1))) unsigned int*)g,
        (__attribute__((address_space(3))) unsigned int*)l,
        16, 0, 0);
}

// ---------------- prepass 1: X f32 -> bf16 ----------------
__global__ __launch_bounds__(256)
void cvt_x(const float* __restrict__ X, unsigned short* __restrict__ Xb, long long n8) {
    long long i0 = (long long)blockIdx.x * 256 + threadIdx.x;
    long long stride = (long long)gridDim.x * 256;
    for (long long i = i0; i < n8; i += stride) {
        const float4* p = reinterpret_cast<const float4*>(X + i * 8);
        float4 a = p[0], b = p[1];
        ushort8 o;
        o[0] = f2bf(a.x); o[1] = f2bf(a.y); o[2] = f2bf(a.z); o[3] = f2bf(a.w);
        o[4] = f2bf(b.x); o[5] = f2bf(b.y); o[6] = f2bf(b.z); o[7] = f2bf(b.w);
        *reinterpret_cast<ushort8*>(Xb + i * 8) = o;
    }
}

// ---------------- prepass 2: qweight -> W^T bf16 [N][K] ----------------
// block tile: 64 n-cols x 64 kp-rows (512 k). Each thread: 16 (n,kp) pairs,
// each pair = one int32 of qweight -> 8 bf16 -> one contiguous ushort8 write.
// Per wave n is fixed -> scales/zeros become scalar loads; W^T writes coalesced.
__global__ __launch_bounds__(256)
void deq_w(const int* __restrict__ QW, const float* __restrict__ SC,
           const int* __restrict__ QZ, unsigned short* __restrict__ WT,
           int N, int K) {
    const int ntiles = N >> 6;
    const int nb = blockIdx.x % ntiles;
    const int kb = blockIdx.x / ntiles;
    const int n0 = nb * 64, kp0 = kb * 64;
    const int t = threadIdx.x;
    #pragma unroll
    for (int w = 0; w < 16; ++w) {
        const int p = t + 256 * w;
        const int kpo = p & 63, ni = p >> 6;
        const int n = n0 + ni, kp = kp0 + kpo;
        const int g = kp >> 4;                       // (kp*8)/128
        const float s = SC[(size_t)g * N + n];
        const int zq = ((QZ[(size_t)g * (N >> 3) + (n >> 3)] >> ((n & 7) * 4)) & 15) + 1;
        const float zb = -(float)zq * s;
        const unsigned int q = (unsigned int)QW[(size_t)kp * N + n];
        ushort8 o;
        #pragma unroll
        for (int j = 0; j < 8; ++j)
            o[j] = f2bf(fmaf((float)((q >> (4 * j)) & 15u), s, zb));
        *reinterpret_cast<ushort8*>(&WT[(size_t)n * K + kp * 8]) = o;
    }
}

// ---------------- main GEMM: bf16 A [M][K] x W^T [N][K] ----------------
__global__ __launch_bounds__(256, 2)
void qgemm_ws(const unsigned short* __restrict__ Xb, const unsigned short* __restrict__ WT,
              const float* __restrict__ BIAS, float* __restrict__ OUT,
              int M, int N, int K) {
    __shared__ __align__(16) unsigned short As[2][128 * 64];
    __shared__ __align__(16) unsigned short Bs[2][128 * 64];

    const int ntn = N >> 7;
    const int bm = (blockIdx.x / ntn) * 128;
    const int bn = (blockIdx.x % ntn) * 128;
    const int tid = threadIdx.x;
    const int lane = tid & 63;
    const int wave = tid >> 6;
    const int wm = (wave >> 1) * 64, wn = (wave & 1) * 64;
    const int lr = lane & 15, lk = (lane >> 4) * 8;

    f32x4 acc[4][4] = {};
    const int nk = K >> 6;

    // 16KB per tile = 4 x (256 threads x 16B). LDS dest linear (base+lane*16);
    // global source pre-swizzled (c ^ row&7) so read-side XOR lands on the right data.
    auto stage = [&](int buf, int t) {
        const int k0 = t * 64;
        #pragma unroll
        for (int p = 0; p < 4; ++p) {
            const int slot = p * 256 + tid;
            const int row = slot >> 3, c = slot & 7;
            const int gk = k0 + ((c ^ (row & 7)) << 3);
            gld16(Xb + (size_t)(bm + row) * K + gk, &As[buf][slot * 8]);
            gld16(WT + (size_t)(bn + row) * K + gk, &Bs[buf][slot * 8]);
        }
    };

    auto compute = [&](int buf) {
        #pragma unroll
        for (int kk = 0; kk < 2; ++kk) {
            bf16x8 af[4], bfr[4];
            #pragma unroll
            for (int i = 0; i < 4; ++i) {
                af[i]  = *reinterpret_cast<const bf16x8*>(&As[buf][swz(wm + i * 16 + lr, kk * 32 + lk)]);
                bfr[i] = *reinterpret_cast<const bf16x8*>(&Bs[buf][swz(wn + i * 16 + lr, kk * 32 + lk)]);
            }
            #pragma unroll
            for (int i = 0; i < 4; ++i)
                #pragma unroll
                for (int j = 0; j < 4; ++j)
                    acc[i][j] = __builtin_amdgcn_mfma_f32_16x16x32_bf16(af[i], bfr[j], acc[i][j], 0, 0, 0);
        }
    };

    stage(0, 0);
    __syncthreads();
    int cur = 0;
    for (int t = 0; t < nk; ++t) {
        if (t + 1 < nk) stage(cur ^ 1, t + 1);
        compute(cur);
        __syncthreads();        // drains vmcnt(0)+lgkmcnt(0): next tile staged, reads done
        cur ^= 1;
    }

    // epilogue: C/D layout col=lane&15, row=(lane>>4)*4+reg
    #pragma unroll
    for (int i = 0; i < 4; ++i) {
        #pragma unroll
        for (int j = 0; j < 4; ++j) {
            const int col = bn + wn + j * 16 + lr;
            const float b = BIAS[col];
            #pragma unroll
            for (int r = 0; r < 4; ++r) {
                const int row = bm + wm + i * 16 + (lane >> 4) * 4 + r;
                OUT[(size_t)row * N + col] = acc[i][j][r] + b;
            }
        }
    }
}

// ---------------- fallback (round-1 kernel, used when ws too small) ----------------
__global__ __launch_bounds__(256, 2)
void qgemm_fb(const float* __restrict__ X, const int* __restrict__ QW,
              const float* __restrict__ SC, const int* __restrict__ QZ,
              const float* __restrict__ BIAS, float* __restrict__ OUT,
              int M, int N, int K) {
    __shared__ __align__(16) unsigned short As[2][128 * 64];
    __shared__ __align__(16) unsigned short Bs[2][128 * 64];

    const int ntn = N / 128;
    const int bm = (blockIdx.x / ntn) * 128;
    const int bn = (blockIdx.x % ntn) * 128;

    const int tid  = threadIdx.x;
    const int lane = tid & 63;
    const int wave = tid >> 6;
    const int wm = (wave >> 1) * 64;
    const int wn = (wave & 1) * 64;
    const int lr = lane & 15;
    const int lk = (lane >> 4) * 8;

    const int a_c4 = tid & 15;
    const int a_r0 = tid >> 4;
    const int b_n  = tid & 127;
    const int b_k0 = tid >> 7;

    f32x4 acc[4][4] = {};
    float4 va[8];
    unsigned int wb[4];
    float sc_s = 0.f, sc_zb = 0.f;
    const int nk = K / 64;

    auto gload = [&](int t) {
        const int k0 = t * 64;
        #pragma unroll
        for (int p = 0; p < 8; ++p) {
            const float* src = X + (size_t)(bm + a_r0 + p * 16) * K + k0 + a_c4 * 4;
            va[p] = *reinterpret_cast<const float4*>(src);
        }
        const int g  = k0 >> 7;
        const int gn = bn + b_n;
        sc_s = SC[(size_t)g * N + gn];
        const int zq = ((QZ[(size_t)g * (N >> 3) + (gn >> 3)] >> ((gn & 7) * 4)) & 15) + 1;
        sc_zb = -(float)zq * sc_s;
        #pragma unroll
        for (int p = 0; p < 4; ++p) {
            const int ko = b_k0 + p * 2;
            wb[p] = (unsigned int)QW[(size_t)(t * 8 + ko) * N + gn];
        }
    };

    auto lwrite = [&](int buf) {
        #pragma unroll
        for (int p = 0; p < 8; ++p) {
            const int row = a_r0 + p * 16;
            ushort4v b;
            b.x = f2bf(va[p].x); b.y = f2bf(va[p].y);
            b.z = f2bf(va[p].z); b.w = f2bf(va[p].w);
            *reinterpret_cast<ushort4v*>(&As[buf][swz(row, a_c4 * 4)]) = b;
        }
        #pragma unroll
        for (int p = 0; p < 4; ++p) {
            const int ko = b_k0 + p * 2;
            ushort8 o;
            #pragma unroll
            for (int j = 0; j < 8; ++j) {
                const float q = (float)((wb[p] >> (4 * j)) & 15u);
                o[j] = f2bf(fmaf(q, sc_s, sc_zb));
            }
            *reinterpret_cast<ushort8*>(&Bs[buf][swz(b_n, ko * 8)]) = o;
        }
    };

    auto compute = [&](int buf) {
        #pragma unroll
        for (int kk = 0; kk < 2; ++kk) {
            bf16x8 af[4], bfr[4];
            #pragma unroll
            for (int i = 0; i < 4; ++i) {
                af[i]  = *reinterpret_cast<const bf16x8*>(&As[buf][swz(wm + i * 16 + lr, kk * 32 + lk)]);
                bfr[i] = *reinterpret_cast<const bf16x8*>(&Bs[buf][swz(wn + i * 16 + lr, kk * 32 + lk)]);
            }
            #pragma unroll
            for (int i = 0; i < 4; ++i)
                #pragma unroll
                for (int j = 0; j < 4; ++j)
                    acc[i][j] = __builtin_amdgcn_mfma_f32_16x16x32_bf16(af[i], bfr[j], acc[i][j], 0, 0, 0);
        }
    };

    gload(0);
    lwrite(0);
    __syncthreads();

    for (int t = 0; t < nk; ++t) {
        if (t + 1 < nk) gload(t + 1);
        compute(t & 1);
        if (t + 1 < nk) lwrite((t + 1) & 1);
        __syncthreads();
    }

    #pragma unroll
    for (int i = 0; i < 4; ++i) {
        #pragma unroll
        for (int j = 0; j < 4; ++j) {
            const int col = bn + wn + j * 16 + lr;
            const float b = BIAS[col];
            #pragma unroll
            for (int r = 0; r < 4; ++r) {
                const int row = bm + wm + i * 16 + (lane >> 4) * 4 + r;
                OUT[(size_t)row * N + col] = acc[i][j][r] + b;
            }
        }
    }
}

extern "C" void kernel_launch(void* const* d_in, const int* in_sizes, int n_in,
                              void* d_out, int out_size, void* d_ws, size_t ws_size,
                              hipStream_t stream) {
    const float* X    = (const float*)d_in[0];
    const int*   QW   = (const int*)d_in[1];
    const float* SC   = (const float*)d_in[2];
    const int*   QZ   = (const int*)d_in[3];
    const float* BIAS = (const float*)d_in[4];
    float* OUT = (float*)d_out;

    const int N = in_sizes[4];                        // 11008
    const long long qwsz = in_sizes[1];               // (K/8)*N
    const int K = (int)(qwsz * 8 / N);                // 4096
    const int M = in_sizes[0] / K;                    // 8192

    const size_t xb_bytes = (size_t)M * K * 2;
    const size_t wt_bytes = (size_t)N * K * 2;

    if (ws_size >= xb_bytes + wt_bytes) {
        unsigned short* Xb = (unsigned short*)d_ws;
        unsigned short* WT = Xb + (size_t)M * K;

        cvt_x<<<2048, 256, 0, stream>>>(X, Xb, (long long)M * K / 8);
        deq_w<<<(N >> 6) * (K / 512), 256, 0, stream>>>(QW, SC, QZ, WT, N, K);
        qgemm_ws<<<(M / 128) * (N / 128), 256, 0, stream>>>(Xb, WT, BIAS, OUT, M, N, K);
    } else {
        qgemm_fb<<<(M / 128) * (N / 128), 256, 0, stream>>>(X, QW, SC, QZ, BIAS, OUT, M, N, K);
    }
}